// Round 12
// baseline (400.588 us; speedup 1.0000x reference)
//
#include <hip/hip_runtime.h>
#include <hip/hip_bf16.h>
#include <math.h>

// Problem constants (fixed by the reference)
#define LTOT 4096   // H*W = 64*64
#define DCH  96     // d_inner
#define NST  16     // d_state
#define RNK  6      // dt_rank
#define CPR  38     // R + 2N
#define KDIR 4
#define NCH  16     // scan chunks per (s,b,d)  (= waves per block)
#define CHUNK (LTOT / NCH)   // 256 steps per chunk

// Direction index maps (involutions; also the path_overlay inverse maps).
__device__ __forceinline__ int dir_idx(int k, int l) {
  int a = l >> 6, c = l & 63;          // l = a*64 + c
  if (k == 0) return l;                // HW order
  if (k == 1) return (c << 6) + a;     // WH (transpose) order
  if (k == 2) return 4095 - l;         // reversed HW
  return ((63 - c) << 6) + (63 - a);   // reversed WH
}

// DPP row_shl fused add: lane i += lane i+N within its 16-lane DPP row.
// After stages 8,4,2,1 lane n==0 of each row holds the 16-lane sum.
template <int CTRL>
__device__ __forceinline__ float row_shl_add(float p) {
  int moved = __builtin_amdgcn_update_dpp(0, __float_as_int(p), CTRL, 0xF, 0xF, true);
  return p + __int_as_float(moved);
}
__device__ __forceinline__ float reduce16(float p) {
  p = row_shl_add<0x108>(p);  // row_shl:8
  p = row_shl_add<0x104>(p);  // row_shl:4
  p = row_shl_add<0x102>(p);  // row_shl:2
  p = row_shl_add<0x101>(p);  // row_shl:1
  return p;
}

// ---------------------------------------------------------------------------
// Kernel 0: per-plane 64x64 transpose of x and y into xT (aliases yyBuf --
// xT is consumed by proj before scan overwrites the region with yy output).
// xT[((s*4+b)*96+d)*4096 + w*64+h] = xin[(b*96+d)*4096 + h*64+w]
// ---------------------------------------------------------------------------
__global__ __launch_bounds__(256) void transpose_kernel(
    const float* __restrict__ x, const float* __restrict__ y,
    float* __restrict__ xT)
{
  __shared__ float t[64][65];
  int plane = blockIdx.x;                 // (s*4+b)*96 + d
  int s = plane / (4 * DCH);
  int rem = plane - s * 4 * DCH;          // b*96 + d
  const float* src = (s ? y : x) + (size_t)rem * LTOT;
  float* dst = xT + (size_t)plane * LTOT;
  int tid = threadIdx.x;

  #pragma unroll
  for (int i = 0; i < 4; ++i) {
    int f4 = i * 256 + tid;               // float4 index: floats f4*4 .. +3
    float4 v = ((const float4*)src)[f4];
    int h = (f4 * 4) >> 6, w = (f4 * 4) & 63;
    t[h][w]     = v.x;
    t[h][w + 1] = v.y;
    t[h][w + 2] = v.z;
    t[h][w + 3] = v.w;
  }
  __syncthreads();
  #pragma unroll
  for (int i = 0; i < 4; ++i) {
    int o4 = i * 256 + tid;               // dst float4 index
    int w = o4 >> 4, h0 = (o4 & 15) * 4;
    float4 r = make_float4(t[h0][w], t[h0 + 1][w], t[h0 + 2][w], t[h0 + 3][w]);
    ((float4*)dst)[o4] = r;
  }
}

// ---------------------------------------------------------------------------
// Kernel 1: projections.  thread = one l for one (s,b,k).
// x reads fully coalesced for ALL k: k&1 -> transposed plane xT (linear),
// k&2 -> reversed-linear.  delta [s][b][k][d][l]; B/C interleaved [l][n].
// ---------------------------------------------------------------------------
__global__ __launch_bounds__(256) void proj_kernel(
    const float* __restrict__ x, const float* __restrict__ y,
    const float* __restrict__ xT,
    const float* __restrict__ xw_d, const float* __restrict__ dtw_d, const float* __restrict__ dtb_d,
    const float* __restrict__ xw_c, const float* __restrict__ dtw_c, const float* __restrict__ dtb_c,
    float* __restrict__ deltaBuf, float* __restrict__ BBuf, float* __restrict__ CBuf)
{
  int l  = blockIdx.x * 256 + threadIdx.x;
  int k  = blockIdx.y;
  int sb = blockIdx.z;
  int s  = sb >> 2, b = sb & 3;

  const float* xw  = s ? xw_c  : xw_d;   // [K][38][96]
  const float* dtw = s ? dtw_c : dtw_d;  // [K][96][6]
  const float* dtb = s ? dtb_c : dtb_d;  // [K][96]

  // coalesced source: transposed plane for k=1,3; reversed index for k=2,3
  const float* xb = (k & 1) ? (xT + (size_t)(s * 4 + b) * DCH * LTOT)
                            : ((s ? y : x) + (size_t)b * DCH * LTOT);
  int pos = (k & 2) ? (4095 - l) : l;

  float acc[CPR];
  #pragma unroll
  for (int c = 0; c < CPR; ++c) acc[c] = 0.f;

  const float* Wk = xw + k * CPR * DCH;
  for (int d = 0; d < DCH; ++d) {
    float xv = xb[(size_t)d * LTOT + pos];
    #pragma unroll
    for (int c = 0; c < CPR; ++c) acc[c] = fmaf(xv, Wk[c * DCH + d], acc[c]);
  }

  const float* dwk = dtw + k * DCH * RNK;
  const float* dbk = dtb + k * DCH;
  float* dOut = deltaBuf + ((size_t)((s * 4 + b) * KDIR + k) * DCH) * LTOT + l;
  for (int d = 0; d < DCH; ++d) {
    float t = dbk[d];
    #pragma unroll
    for (int r = 0; r < RNK; ++r) t = fmaf(acc[r], dwk[d * RNK + r], t);
    float sp = (t > 20.f) ? t : log1pf(__expf(t));   // softplus
    dOut[(size_t)d * LTOT] = sp;
  }

  // interleaved [l][n] writes: fully coalesced float4s
  float* Bo = BBuf + ((size_t)((s * 4 + b) * KDIR + k) * LTOT + l) * NST;
  float* Co = CBuf + ((size_t)((s * 4 + b) * KDIR + k) * LTOT + l) * NST;
  #pragma unroll
  for (int q = 0; q < 4; ++q) {
    float4 bv = make_float4(acc[RNK + 4*q], acc[RNK + 4*q+1], acc[RNK + 4*q+2], acc[RNK + 4*q+3]);
    float4 cv = make_float4(acc[RNK+NST + 4*q], acc[RNK+NST + 4*q+1], acc[RNK+NST + 4*q+2], acc[RNK+NST + 4*q+3]);
    ((float4*)Bo)[q] = bv;
    ((float4*)Co)[q] = cv;
  }
}

// ---------------------------------------------------------------------------
// Kernel 2: chunked selective scan + in-kernel path overlay (UNCHANGED from
// round 10: 237 us, VALU-issue-bound plateau).
// ---------------------------------------------------------------------------
__global__ __launch_bounds__(1024) void scan_kernel(
    const float* __restrict__ x, const float* __restrict__ y,
    const float* __restrict__ Alog_d, const float* __restrict__ Ds_d,
    const float* __restrict__ Alog_c, const float* __restrict__ Ds_c,
    const float* __restrict__ deltaBuf, const float* __restrict__ BBuf,
    const float* __restrict__ CBuf, float* __restrict__ yyBuf)
{
  __shared__ float yy[LTOT];        // 16 KB merged overlay accumulator
  __shared__ float xrow[LTOT];      // 16 KB staged x row
  __shared__ float hloc[NCH][64];
  __shared__ float Pc[NCH][64];
  __shared__ float hin[NCH][64];

  int tid  = threadIdx.x;
  int c    = tid >> 6;              // chunk id = wave id
  int lane = tid & 63;
  int k = lane >> 4, n = lane & 15;
  int d = blockIdx.x, b = blockIdx.y, s = blockIdx.z;

  const float* xin  = s ? y      : x;
  const float* Alog = s ? Alog_c : Alog_d;
  const float* Dsp  = s ? Ds_c   : Ds_d;

  float A2 = -__expf(Alog[(k * DCH + d) * NST + n]) * 1.44269504088896341f; // A*log2(e)

  // cooperative init: zero yy, stage x row (coalesced float4)
  const float* xb = xin + (size_t)(b * DCH + d) * LTOT;
  {
    float4 xv = ((const float4*)xb)[tid];
    ((float4*)xrow)[tid] = xv;
    ((float4*)yy)[tid] = make_float4(0.f, 0.f, 0.f, 0.f);
  }
  __syncthreads();

  const float* dbase = deltaBuf + ((size_t)(((s * 4 + b) * KDIR + k) * DCH + d)) * LTOT;
  const float* Bbase = BBuf + ((size_t)((s * 4 + b) * KDIR + k)) * LTOT * NST;
  const float* Cbase = CBuf + ((size_t)(((1 - s) * 4 + b) * KDIR + k)) * LTOT * NST; // crossed
  const int l0beg = c * CHUNK;

  // incremental pos (byte offsets): per-k step delta; row-end wrap correction
  const int dpn  = (k & 2 ? -1 : 1) * (k & 1 ? 64 : 1);
  const int dpw  = (k & 1) ? ((k & 2) ? 4031 : -4031) : dpn;
  const int dpnB = dpn * 4, dpwB = dpw * 4;
  const int rowFix = dpwB - dpnB;    // 0 for k=0,2

  // ---- phase 1: local scan (h0=0), accumulate sum of delta ----
  float h = 0.f, sumd = 0.f;
  {
    int posB = dir_idx(k, l0beg) * 4;
    const float* dp = dbase + l0beg;
    const float* Bp = Bbase + (size_t)l0beg * NST + n;
    for (int row = 0; row < CHUNK / 64; ++row) {
      #pragma unroll 8
      for (int g = 0; g < 16; ++g) {
        float4 dv = *(const float4*)dp;  dp += 4;
        float b0 = Bp[0 * NST], b1 = Bp[1 * NST], b2 = Bp[2 * NST], b3 = Bp[3 * NST];
        Bp += 4 * NST;
        float u;
        u = *(const float*)((const char*)xrow + posB); posB += dpnB;
        sumd += dv.x; h = fmaf(h, exp2f(dv.x * A2), dv.x * u * b0);
        u = *(const float*)((const char*)xrow + posB); posB += dpnB;
        sumd += dv.y; h = fmaf(h, exp2f(dv.y * A2), dv.y * u * b1);
        u = *(const float*)((const char*)xrow + posB); posB += dpnB;
        sumd += dv.z; h = fmaf(h, exp2f(dv.z * A2), dv.z * u * b2);
        u = *(const float*)((const char*)xrow + posB); posB += dpnB;
        sumd += dv.w; h = fmaf(h, exp2f(dv.w * A2), dv.w * u * b3);
      }
      posB += rowFix;   // unconditional row-end wrap correction
    }
  }
  hloc[c][lane] = h;
  Pc[c][lane]   = exp2f(A2 * sumd);
  __syncthreads();

  // ---- phase 2: carry scan over chunks (wave 0; exact, linear recurrence) ----
  if (tid < 64) {
    float hh = 0.f;
    hin[0][lane] = 0.f;
    for (int cc = 1; cc < NCH; ++cc) {
      hh = fmaf(Pc[cc - 1][lane], hh, hloc[cc - 1][lane]);
      hin[cc][lane] = hh;
    }
  }
  __syncthreads();

  // ---- phase 3: full scan from true carry-in, y + overlay ----
  h = hin[c][lane];
  {
    int posB = dir_idx(k, l0beg) * 4;
    const float* dp = dbase + l0beg;
    const float* Bp = Bbase + (size_t)l0beg * NST + n;
    const float* Cp = Cbase + (size_t)l0beg * NST + n;
    for (int row = 0; row < CHUNK / 64; ++row) {
      #pragma unroll 4
      for (int g = 0; g < 16; ++g) {
        float4 dv = *(const float4*)dp;  dp += 4;
        float b0 = Bp[0 * NST], b1 = Bp[1 * NST], b2 = Bp[2 * NST], b3 = Bp[3 * NST];
        float c0 = Cp[0 * NST], c1 = Cp[1 * NST], c2 = Cp[2 * NST], c3 = Cp[3 * NST];
        Bp += 4 * NST;  Cp += 4 * NST;
        int q0 = posB;
        float u0 = *(const float*)((const char*)xrow + q0);
        h = fmaf(h, exp2f(dv.x * A2), dv.x * u0 * b0);
        float p0 = h * c0;
        int q1 = q0 + dpnB;
        float u1 = *(const float*)((const char*)xrow + q1);
        h = fmaf(h, exp2f(dv.y * A2), dv.y * u1 * b1);
        float p1 = h * c1;
        int q2 = q1 + dpnB;
        float u2 = *(const float*)((const char*)xrow + q2);
        h = fmaf(h, exp2f(dv.z * A2), dv.z * u2 * b2);
        float p2 = h * c2;
        int q3 = q2 + dpnB;
        float u3 = *(const float*)((const char*)xrow + q3);
        h = fmaf(h, exp2f(dv.w * A2), dv.w * u3 * b3);
        float p3 = h * c3;
        posB = q3 + dpnB;
        // 4 independent DPP trees (ILP), then one masked atomic block
        p0 = reduce16(p0);
        p1 = reduce16(p1);
        p2 = reduce16(p2);
        p3 = reduce16(p3);
        if (n == 0) {
          atomicAdd((float*)((char*)yy + q0), p0);
          atomicAdd((float*)((char*)yy + q1), p1);
          atomicAdd((float*)((char*)yy + q2), p2);
          atomicAdd((float*)((char*)yy + q3), p3);
        }
      }
      posB += rowFix;   // unconditional row-end wrap correction
    }
  }
  __syncthreads();

  // writeback with hoisted D-skip term: sum_k u*Dv_k = xrow[m] * Dsum
  float Dsum = Dsp[0 * DCH + d] + Dsp[1 * DCH + d] + Dsp[2 * DCH + d] + Dsp[3 * DCH + d];
  float* out = yyBuf + (size_t)((s * 4 + b) * DCH + d) * LTOT;
  {
    float4 v  = ((const float4*)yy)[tid];
    float4 xv = ((const float4*)xrow)[tid];
    v.x = fmaf(xv.x, Dsum, v.x);
    v.y = fmaf(xv.y, Dsum, v.y);
    v.z = fmaf(xv.z, Dsum, v.z);
    v.w = fmaf(xv.w, Dsum, v.w);
    ((float4*)out)[tid] = v;
  }
}

// ---------------------------------------------------------------------------
// Kernel 3: layernorm over channels + final transpose to [B,D,H,W].
// ---------------------------------------------------------------------------
__global__ __launch_bounds__(256) void merge_ln_kernel(
    const float* __restrict__ yyBuf,
    const float* __restrict__ ln1s, const float* __restrict__ ln1b,
    const float* __restrict__ ln2s, const float* __restrict__ ln2b,
    float* __restrict__ out)
{
  int p = blockIdx.x * 256 + threadIdx.x;
  int b = blockIdx.y, s = blockIdx.z;

  const float* base = yyBuf + ((size_t)(s * 4 + b) * DCH) * LTOT + p;
  float v[DCH];
  float m = 0.f;
  #pragma unroll
  for (int d = 0; d < DCH; ++d) { v[d] = base[(size_t)d * LTOT]; m += v[d]; }
  m *= (1.f / DCH);
  float var = 0.f;
  #pragma unroll
  for (int d = 0; d < DCH; ++d) { float t = v[d] - m; var = fmaf(t, t, var); }
  var *= (1.f / DCH);
  float r = rsqrtf(var + 1e-5f);

  const float* sc = s ? ln2s : ln1s;
  const float* bi = s ? ln2b : ln1b;
  float* ob = out + ((size_t)(s * 4 + b) * DCH) * LTOT + p;
  #pragma unroll
  for (int d = 0; d < DCH; ++d) ob[(size_t)d * LTOT] = (v[d] - m) * r * sc[d] + bi[d];
}

// ---------------------------------------------------------------------------
extern "C" void kernel_launch(void* const* d_in, const int* in_sizes, int n_in,
                              void* d_out, int out_size, void* d_ws, size_t ws_size,
                              hipStream_t stream)
{
  const float* x      = (const float*)d_in[0];
  const float* y      = (const float*)d_in[1];
  const float* xw_d   = (const float*)d_in[2];
  const float* dtw_d  = (const float*)d_in[3];
  const float* dtb_d  = (const float*)d_in[4];
  const float* Alog_d = (const float*)d_in[5];
  const float* Ds_d   = (const float*)d_in[6];
  const float* xw_c   = (const float*)d_in[7];
  const float* dtw_c  = (const float*)d_in[8];
  const float* dtb_c  = (const float*)d_in[9];
  const float* Alog_c = (const float*)d_in[10];
  const float* Ds_c   = (const float*)d_in[11];
  const float* ln1s   = (const float*)d_in[12];
  const float* ln1b   = (const float*)d_in[13];
  const float* ln2s   = (const float*)d_in[14];
  const float* ln2b   = (const float*)d_in[15];

  float* ws = (float*)d_ws;
  float* deltaBuf = ws;
  float* BBuf  = deltaBuf + (size_t)2 * 4 * KDIR * DCH * LTOT;
  float* CBuf  = BBuf + (size_t)2 * 4 * KDIR * NST * LTOT;
  float* yyBuf = CBuf + (size_t)2 * 4 * KDIR * NST * LTOT;
  float* xT    = yyBuf;   // alias: xT consumed by proj BEFORE scan writes yy
  float* outF  = (float*)d_out;

  hipLaunchKernelGGL(transpose_kernel, dim3(2 * 4 * DCH), dim3(256), 0, stream,
                     x, y, xT);

  dim3 pg(LTOT / 256, KDIR, 8);   // (l-chunks, k, s*4+b)
  hipLaunchKernelGGL(proj_kernel, pg, dim3(256), 0, stream,
                     x, y, xT, xw_d, dtw_d, dtb_d, xw_c, dtw_c, dtb_c,
                     deltaBuf, BBuf, CBuf);

  dim3 sg(DCH, 4, 2);             // (d, b, s): one 16-wave block each
  hipLaunchKernelGGL(scan_kernel, sg, dim3(1024), 0, stream,
                     x, y, Alog_d, Ds_d, Alog_c, Ds_c,
                     deltaBuf, BBuf, CBuf, yyBuf);

  dim3 mg(LTOT / 256, 4, 2);      // (p-chunks, b, s)
  hipLaunchKernelGGL(merge_ln_kernel, mg, dim3(256), 0, stream,
                     yyBuf, ln1s, ln1b, ln2s, ln2b, outF);
}

// Round 14
// 374.616 us; speedup vs baseline: 1.0693x; 1.0693x over previous
//
#include <hip/hip_runtime.h>
#include <hip/hip_bf16.h>
#include <math.h>

// Problem constants (fixed by the reference)
#define LTOT 4096   // H*W = 64*64
#define DCH  96     // d_inner
#define NST  16     // d_state
#define RNK  6      // dt_rank
#define CPR  38     // R + 2N
#define KDIR 4
#define NCH  16     // scan chunks per (s,b,d)  (= waves per block)
#define CHUNK (LTOT / NCH)   // 256 steps per chunk

// Fast exp: __expf is HIP's native-exp (v_mul by log2e + v_exp_f32) and the
// compiler handles the TRANS-op hazard wait-states. NOTE: round-13's inline
// "v_exp_f32" asm was NOT hazard-safe (nondeterministic divergence under
// graph replay) -- never hand-emit TRANS ops via opaque asm.
__device__ __forceinline__ float exp_fast(float x) { return __expf(x); }

// Direction index maps (involutions; also the path_overlay inverse maps).
__device__ __forceinline__ int dir_idx(int k, int l) {
  int a = l >> 6, c = l & 63;          // l = a*64 + c
  if (k == 0) return l;                // HW order
  if (k == 1) return (c << 6) + a;     // WH (transpose) order
  if (k == 2) return 4095 - l;         // reversed HW
  return ((63 - c) << 6) + (63 - a);   // reversed WH
}

// DPP row_shl fused add: lane i += lane i+N within its 16-lane DPP row.
// After stages 8,4,2,1 lane n==0 of each row holds the 16-lane sum.
template <int CTRL>
__device__ __forceinline__ float row_shl_add(float p) {
  int moved = __builtin_amdgcn_update_dpp(0, __float_as_int(p), CTRL, 0xF, 0xF, true);
  return p + __int_as_float(moved);
}
__device__ __forceinline__ float reduce16(float p) {
  p = row_shl_add<0x108>(p);  // row_shl:8
  p = row_shl_add<0x104>(p);  // row_shl:4
  p = row_shl_add<0x102>(p);  // row_shl:2
  p = row_shl_add<0x101>(p);  // row_shl:1
  return p;
}

// ---------------------------------------------------------------------------
// Kernel 0: per-plane 64x64 transpose of x and y into xT (aliases yyBuf --
// xT is consumed by proj before scan overwrites the region with yy output).
// ---------------------------------------------------------------------------
__global__ __launch_bounds__(256) void transpose_kernel(
    const float* __restrict__ x, const float* __restrict__ y,
    float* __restrict__ xT)
{
  __shared__ float t[64][65];
  int plane = blockIdx.x;                 // (s*4+b)*96 + d
  int s = plane / (4 * DCH);
  int rem = plane - s * 4 * DCH;          // b*96 + d
  const float* src = (s ? y : x) + (size_t)rem * LTOT;
  float* dst = xT + (size_t)plane * LTOT;
  int tid = threadIdx.x;

  #pragma unroll
  for (int i = 0; i < 4; ++i) {
    int f4 = i * 256 + tid;               // float4 index: floats f4*4 .. +3
    float4 v = ((const float4*)src)[f4];
    int h = (f4 * 4) >> 6, w = (f4 * 4) & 63;
    t[h][w]     = v.x;
    t[h][w + 1] = v.y;
    t[h][w + 2] = v.z;
    t[h][w + 3] = v.w;
  }
  __syncthreads();
  #pragma unroll
  for (int i = 0; i < 4; ++i) {
    int o4 = i * 256 + tid;               // dst float4 index
    int w = o4 >> 4, h0 = (o4 & 15) * 4;
    float4 r = make_float4(t[h0][w], t[h0 + 1][w], t[h0 + 2][w], t[h0 + 3][w]);
    ((float4*)dst)[o4] = r;
  }
}

// ---------------------------------------------------------------------------
// Kernel 1: projections.  thread = one l for one (s,b,k).
// x reads fully coalesced for ALL k: k&1 -> transposed plane xT (linear),
// k&2 -> reversed-linear.  delta [s][b][k][d][l]; B/C interleaved [l][n].
// ---------------------------------------------------------------------------
__global__ __launch_bounds__(256) void proj_kernel(
    const float* __restrict__ x, const float* __restrict__ y,
    const float* __restrict__ xT,
    const float* __restrict__ xw_d, const float* __restrict__ dtw_d, const float* __restrict__ dtb_d,
    const float* __restrict__ xw_c, const float* __restrict__ dtw_c, const float* __restrict__ dtb_c,
    float* __restrict__ deltaBuf, float* __restrict__ BBuf, float* __restrict__ CBuf)
{
  int l  = blockIdx.x * 256 + threadIdx.x;
  int k  = blockIdx.y;
  int sb = blockIdx.z;
  int s  = sb >> 2, b = sb & 3;

  const float* xw  = s ? xw_c  : xw_d;   // [K][38][96]
  const float* dtw = s ? dtw_c : dtw_d;  // [K][96][6]
  const float* dtb = s ? dtb_c : dtb_d;  // [K][96]

  // coalesced source: transposed plane for k=1,3; reversed index for k=2,3
  const float* xb = (k & 1) ? (xT + (size_t)(s * 4 + b) * DCH * LTOT)
                            : ((s ? y : x) + (size_t)b * DCH * LTOT);
  int pos = (k & 2) ? (4095 - l) : l;

  float acc[CPR];
  #pragma unroll
  for (int c = 0; c < CPR; ++c) acc[c] = 0.f;

  const float* Wk = xw + k * CPR * DCH;
  for (int d = 0; d < DCH; ++d) {
    float xv = xb[(size_t)d * LTOT + pos];
    #pragma unroll
    for (int c = 0; c < CPR; ++c) acc[c] = fmaf(xv, Wk[c * DCH + d], acc[c]);
  }

  const float* dwk = dtw + k * DCH * RNK;
  const float* dbk = dtb + k * DCH;
  float* dOut = deltaBuf + ((size_t)((s * 4 + b) * KDIR + k) * DCH) * LTOT + l;
  for (int d = 0; d < DCH; ++d) {
    float t = dbk[d];
    #pragma unroll
    for (int r = 0; r < RNK; ++r) t = fmaf(acc[r], dwk[d * RNK + r], t);
    float sp = (t > 20.f) ? t : log1pf(__expf(t));   // softplus
    dOut[(size_t)d * LTOT] = sp;
  }

  // interleaved [l][n] writes: fully coalesced float4s
  float* Bo = BBuf + ((size_t)((s * 4 + b) * KDIR + k) * LTOT + l) * NST;
  float* Co = CBuf + ((size_t)((s * 4 + b) * KDIR + k) * LTOT + l) * NST;
  #pragma unroll
  for (int q = 0; q < 4; ++q) {
    float4 bv = make_float4(acc[RNK + 4*q], acc[RNK + 4*q+1], acc[RNK + 4*q+2], acc[RNK + 4*q+3]);
    float4 cv = make_float4(acc[RNK+NST + 4*q], acc[RNK+NST + 4*q+1], acc[RNK+NST + 4*q+2], acc[RNK+NST + 4*q+3]);
    ((float4*)Bo)[q] = bv;
    ((float4*)Co)[q] = cv;
  }
}

// ---------------------------------------------------------------------------
// Kernel 2: chunked selective scan + in-kernel path overlay.  Identical
// structure to the 236-us round-10 version; per-step exp via __expf
// (native v_exp_f32 with compiler-managed hazards; ~20-inst OCML guard gone).
// ---------------------------------------------------------------------------
__global__ __launch_bounds__(1024) void scan_kernel(
    const float* __restrict__ x, const float* __restrict__ y,
    const float* __restrict__ Alog_d, const float* __restrict__ Ds_d,
    const float* __restrict__ Alog_c, const float* __restrict__ Ds_c,
    const float* __restrict__ deltaBuf, const float* __restrict__ BBuf,
    const float* __restrict__ CBuf, float* __restrict__ yyBuf)
{
  __shared__ float yy[LTOT];        // 16 KB merged overlay accumulator
  __shared__ float xrow[LTOT];      // 16 KB staged x row
  __shared__ float hloc[NCH][64];
  __shared__ float Pc[NCH][64];
  __shared__ float hin[NCH][64];

  int tid  = threadIdx.x;
  int c    = tid >> 6;              // chunk id = wave id
  int lane = tid & 63;
  int k = lane >> 4, n = lane & 15;
  int d = blockIdx.x, b = blockIdx.y, s = blockIdx.z;

  const float* xin  = s ? y      : x;
  const float* Alog = s ? Alog_c : Alog_d;
  const float* Dsp  = s ? Ds_c   : Ds_d;

  float A = -__expf(Alog[(k * DCH + d) * NST + n]);   // natural-log domain

  // cooperative init: zero yy, stage x row (coalesced float4)
  const float* xb = xin + (size_t)(b * DCH + d) * LTOT;
  {
    float4 xv = ((const float4*)xb)[tid];
    ((float4*)xrow)[tid] = xv;
    ((float4*)yy)[tid] = make_float4(0.f, 0.f, 0.f, 0.f);
  }
  __syncthreads();

  const float* dbase = deltaBuf + ((size_t)(((s * 4 + b) * KDIR + k) * DCH + d)) * LTOT;
  const float* Bbase = BBuf + ((size_t)((s * 4 + b) * KDIR + k)) * LTOT * NST;
  const float* Cbase = CBuf + ((size_t)(((1 - s) * 4 + b) * KDIR + k)) * LTOT * NST; // crossed
  const int l0beg = c * CHUNK;

  // incremental pos (byte offsets): per-k step delta; row-end wrap correction
  const int dpn  = (k & 2 ? -1 : 1) * (k & 1 ? 64 : 1);
  const int dpw  = (k & 1) ? ((k & 2) ? 4031 : -4031) : dpn;
  const int dpnB = dpn * 4, dpwB = dpw * 4;
  const int rowFix = dpwB - dpnB;    // 0 for k=0,2

  // ---- phase 1: local scan (h0=0), accumulate sum of delta ----
  float h = 0.f, sumd = 0.f;
  {
    int posB = dir_idx(k, l0beg) * 4;
    const float* dp = dbase + l0beg;
    const float* Bp = Bbase + (size_t)l0beg * NST + n;
    for (int row = 0; row < CHUNK / 64; ++row) {
      #pragma unroll 8
      for (int g = 0; g < 16; ++g) {
        float4 dv = *(const float4*)dp;  dp += 4;
        float b0 = Bp[0 * NST], b1 = Bp[1 * NST], b2 = Bp[2 * NST], b3 = Bp[3 * NST];
        Bp += 4 * NST;
        float u;
        u = *(const float*)((const char*)xrow + posB); posB += dpnB;
        sumd += dv.x; h = fmaf(h, exp_fast(dv.x * A), dv.x * u * b0);
        u = *(const float*)((const char*)xrow + posB); posB += dpnB;
        sumd += dv.y; h = fmaf(h, exp_fast(dv.y * A), dv.y * u * b1);
        u = *(const float*)((const char*)xrow + posB); posB += dpnB;
        sumd += dv.z; h = fmaf(h, exp_fast(dv.z * A), dv.z * u * b2);
        u = *(const float*)((const char*)xrow + posB); posB += dpnB;
        sumd += dv.w; h = fmaf(h, exp_fast(dv.w * A), dv.w * u * b3);
      }
      posB += rowFix;   // unconditional row-end wrap correction
    }
  }
  hloc[c][lane] = h;
  Pc[c][lane]   = exp_fast(A * sumd);
  __syncthreads();

  // ---- phase 2: carry scan over chunks (wave 0; exact, linear recurrence) ----
  if (tid < 64) {
    float hh = 0.f;
    hin[0][lane] = 0.f;
    for (int cc = 1; cc < NCH; ++cc) {
      hh = fmaf(Pc[cc - 1][lane], hh, hloc[cc - 1][lane]);
      hin[cc][lane] = hh;
    }
  }
  __syncthreads();

  // ---- phase 3: full scan from true carry-in, y + overlay ----
  h = hin[c][lane];
  {
    int posB = dir_idx(k, l0beg) * 4;
    const float* dp = dbase + l0beg;
    const float* Bp = Bbase + (size_t)l0beg * NST + n;
    const float* Cp = Cbase + (size_t)l0beg * NST + n;
    for (int row = 0; row < CHUNK / 64; ++row) {
      #pragma unroll 4
      for (int g = 0; g < 16; ++g) {
        float4 dv = *(const float4*)dp;  dp += 4;
        float b0 = Bp[0 * NST], b1 = Bp[1 * NST], b2 = Bp[2 * NST], b3 = Bp[3 * NST];
        float c0 = Cp[0 * NST], c1 = Cp[1 * NST], c2 = Cp[2 * NST], c3 = Cp[3 * NST];
        Bp += 4 * NST;  Cp += 4 * NST;
        int q0 = posB;
        float u0 = *(const float*)((const char*)xrow + q0);
        h = fmaf(h, exp_fast(dv.x * A), dv.x * u0 * b0);
        float p0 = h * c0;
        int q1 = q0 + dpnB;
        float u1 = *(const float*)((const char*)xrow + q1);
        h = fmaf(h, exp_fast(dv.y * A), dv.y * u1 * b1);
        float p1 = h * c1;
        int q2 = q1 + dpnB;
        float u2 = *(const float*)((const char*)xrow + q2);
        h = fmaf(h, exp_fast(dv.z * A), dv.z * u2 * b2);
        float p2 = h * c2;
        int q3 = q2 + dpnB;
        float u3 = *(const float*)((const char*)xrow + q3);
        h = fmaf(h, exp_fast(dv.w * A), dv.w * u3 * b3);
        float p3 = h * c3;
        posB = q3 + dpnB;
        // 4 independent DPP trees (ILP), then one masked atomic block
        p0 = reduce16(p0);
        p1 = reduce16(p1);
        p2 = reduce16(p2);
        p3 = reduce16(p3);
        if (n == 0) {
          atomicAdd((float*)((char*)yy + q0), p0);
          atomicAdd((float*)((char*)yy + q1), p1);
          atomicAdd((float*)((char*)yy + q2), p2);
          atomicAdd((float*)((char*)yy + q3), p3);
        }
      }
      posB += rowFix;   // unconditional row-end wrap correction
    }
  }
  __syncthreads();

  // writeback with hoisted D-skip term: sum_k u*Dv_k = xrow[m] * Dsum
  float Dsum = Dsp[0 * DCH + d] + Dsp[1 * DCH + d] + Dsp[2 * DCH + d] + Dsp[3 * DCH + d];
  float* out = yyBuf + (size_t)((s * 4 + b) * DCH + d) * LTOT;
  {
    float4 v  = ((const float4*)yy)[tid];
    float4 xv = ((const float4*)xrow)[tid];
    v.x = fmaf(xv.x, Dsum, v.x);
    v.y = fmaf(xv.y, Dsum, v.y);
    v.z = fmaf(xv.z, Dsum, v.z);
    v.w = fmaf(xv.w, Dsum, v.w);
    ((float4*)out)[tid] = v;
  }
}

// ---------------------------------------------------------------------------
// Kernel 3: layernorm over channels + final transpose to [B,D,H,W].
// ---------------------------------------------------------------------------
__global__ __launch_bounds__(256) void merge_ln_kernel(
    const float* __restrict__ yyBuf,
    const float* __restrict__ ln1s, const float* __restrict__ ln1b,
    const float* __restrict__ ln2s, const float* __restrict__ ln2b,
    float* __restrict__ out)
{
  int p = blockIdx.x * 256 + threadIdx.x;
  int b = blockIdx.y, s = blockIdx.z;

  const float* base = yyBuf + ((size_t)(s * 4 + b) * DCH) * LTOT + p;
  float v[DCH];
  float m = 0.f;
  #pragma unroll
  for (int d = 0; d < DCH; ++d) { v[d] = base[(size_t)d * LTOT]; m += v[d]; }
  m *= (1.f / DCH);
  float var = 0.f;
  #pragma unroll
  for (int d = 0; d < DCH; ++d) { float t = v[d] - m; var = fmaf(t, t, var); }
  var *= (1.f / DCH);
  float r = rsqrtf(var + 1e-5f);

  const float* sc = s ? ln2s : ln1s;
  const float* bi = s ? ln2b : ln1b;
  float* ob = out + ((size_t)(s * 4 + b) * DCH) * LTOT + p;
  #pragma unroll
  for (int d = 0; d < DCH; ++d) ob[(size_t)d * LTOT] = (v[d] - m) * r * sc[d] + bi[d];
}

// ---------------------------------------------------------------------------
extern "C" void kernel_launch(void* const* d_in, const int* in_sizes, int n_in,
                              void* d_out, int out_size, void* d_ws, size_t ws_size,
                              hipStream_t stream)
{
  const float* x      = (const float*)d_in[0];
  const float* y      = (const float*)d_in[1];
  const float* xw_d   = (const float*)d_in[2];
  const float* dtw_d  = (const float*)d_in[3];
  const float* dtb_d  = (const float*)d_in[4];
  const float* Alog_d = (const float*)d_in[5];
  const float* Ds_d   = (const float*)d_in[6];
  const float* xw_c   = (const float*)d_in[7];
  const float* dtw_c  = (const float*)d_in[8];
  const float* dtb_c  = (const float*)d_in[9];
  const float* Alog_c = (const float*)d_in[10];
  const float* Ds_c   = (const float*)d_in[11];
  const float* ln1s   = (const float*)d_in[12];
  const float* ln1b   = (const float*)d_in[13];
  const float* ln2s   = (const float*)d_in[14];
  const float* ln2b   = (const float*)d_in[15];

  float* ws = (float*)d_ws;
  float* deltaBuf = ws;
  float* BBuf  = deltaBuf + (size_t)2 * 4 * KDIR * DCH * LTOT;
  float* CBuf  = BBuf + (size_t)2 * 4 * KDIR * NST * LTOT;
  float* yyBuf = CBuf + (size_t)2 * 4 * KDIR * NST * LTOT;
  float* xT    = yyBuf;   // alias: xT consumed by proj BEFORE scan writes yy
  float* outF  = (float*)d_out;

  hipLaunchKernelGGL(transpose_kernel, dim3(2 * 4 * DCH), dim3(256), 0, stream,
                     x, y, xT);

  dim3 pg(LTOT / 256, KDIR, 8);   // (l-chunks, k, s*4+b)
  hipLaunchKernelGGL(proj_kernel, pg, dim3(256), 0, stream,
                     x, y, xT, xw_d, dtw_d, dtb_d, xw_c, dtw_c, dtb_c,
                     deltaBuf, BBuf, CBuf);

  dim3 sg(DCH, 4, 2);             // (d, b, s): one 16-wave block each
  hipLaunchKernelGGL(scan_kernel, sg, dim3(1024), 0, stream,
                     x, y, Alog_d, Ds_d, Alog_c, Ds_c,
                     deltaBuf, BBuf, CBuf, yyBuf);

  dim3 mg(LTOT / 256, 4, 2);      // (p-chunks, b, s)
  hipLaunchKernelGGL(merge_ln_kernel, mg, dim3(256), 0, stream,
                     yyBuf, ln1s, ln1b, ln2s, ln2b, outF);
}